// Round 2
// baseline (232.981 us; speedup 1.0000x reference)
//
#include <hip/hip_runtime.h>
#include <cstdint>

typedef int v4i __attribute__((ext_vector_type(4)));

#define K_DIM 4096
#define BM 128
#define BN 128
#define BK 64

// ---------------------------------------------------------------------------
// Kernel 0: pack int32 weight (values 1..127) -> int8.
// Each thread: 4x int4 loads (16 int32) -> 1x int4 store (16 int8).
// ---------------------------------------------------------------------------
__global__ __launch_bounds__(256) void pack_weight(
    const int* __restrict__ w32, int8_t* __restrict__ w8, int total16)
{
    const int i = blockIdx.x * 256 + threadIdx.x;   // one per 16 elements
    if (i >= total16) return;
    const v4i* src = reinterpret_cast<const v4i*>(w32) + i * 4;
    v4i out;
#pragma unroll
    for (int j = 0; j < 4; ++j) {
        const v4i v = src[j];
        out[j] = (v.x & 0xff) | ((v.y & 0xff) << 8) |
                 ((v.z & 0xff) << 16) | ((unsigned)(v.w & 0xff) << 24);
    }
    reinterpret_cast<v4i*>(w8)[i] = out;
}

// ---------------------------------------------------------------------------
// Kernel 1: per-row symmetric int8 quantization.
// One block (256 threads) per row of 4096 floats. Each thread: 4x float4.
// ---------------------------------------------------------------------------
__global__ __launch_bounds__(256) void quant_rows(
    const float* __restrict__ x, int8_t* __restrict__ q,
    float* __restrict__ scales)
{
    const int row = blockIdx.x;
    const int t   = threadIdx.x;
    const float4* xr4 = reinterpret_cast<const float4*>(x + (size_t)row * K_DIM);

    float4 v[4];
    float m = 0.0f;
#pragma unroll
    for (int i = 0; i < 4; ++i) {
        v[i] = xr4[i * 256 + t];
        m = fmaxf(m, fmaxf(fmaxf(fabsf(v[i].x), fabsf(v[i].y)),
                           fmaxf(fabsf(v[i].z), fabsf(v[i].w))));
    }
    // wave64 butterfly max
#pragma unroll
    for (int off = 32; off >= 1; off >>= 1)
        m = fmaxf(m, __shfl_xor(m, off, 64));

    __shared__ float wmax[4];
    if ((t & 63) == 0) wmax[t >> 6] = m;
    __syncthreads();
    const float am = fmaxf(fmaxf(wmax[0], wmax[1]), fmaxf(wmax[2], wmax[3]));
    const float s  = fmaxf(am / 127.0f, 1e-8f);   // exact: matches ref absmax/127
    if (t == 0) scales[row] = s;

    int* qi = reinterpret_cast<int*>(q + (size_t)row * K_DIM);
#pragma unroll
    for (int i = 0; i < 4; ++i) {
        const float e[4] = {v[i].x, v[i].y, v[i].z, v[i].w};
        unsigned packed = 0;
#pragma unroll
        for (int j = 0; j < 4; ++j) {
            float r = rintf(e[j] / s);            // round-half-even, exact div
            r = fminf(fmaxf(r, -127.0f), 127.0f);
            packed |= ((unsigned)((int)r & 0xff)) << (8 * j);
        }
        qi[i * 256 + t] = (int)packed;
    }
}

// ---------------------------------------------------------------------------
// Kernel 2: int8 GEMM  C[m][n] = sum_k A[m][k]*B[n][k], both K-contiguous.
// 128x128 tile, BK=64, 4 waves (2x2), each wave owns a 64x64 sub-tile as
// 4x4 fragments of mfma_i32_16x16x64_i8. global_load_lds width=16 staging.
// ---------------------------------------------------------------------------
__global__ __launch_bounds__(256, 2) void gemm_i8(
    const int8_t* __restrict__ A,   // [M][K] quantized activations
    const int8_t* __restrict__ B,   // [N][K] packed weight
    const float* __restrict__ sA,   // [M] per-row scales
    const float* __restrict__ wsc,  // [1] weight scale
    float* __restrict__ C,          // [M][N]
    int M, int N)
{
    __shared__ int8_t ldsA[BM * BK];
    __shared__ int8_t ldsB[BN * BK];

    const int t    = threadIdx.x;
    const int lane = t & 63;
    const int wid  = t >> 6;
    const int wr   = wid >> 1;       // 0..1
    const int wc   = wid & 1;        // 0..1

    const int brow = blockIdx.y * BM;
    const int bcol = blockIdx.x * BN;

    const float ws = wsc[0];

    v4i acc[4][4];
#pragma unroll
    for (int i = 0; i < 4; ++i)
#pragma unroll
        for (int j = 0; j < 4; ++j)
            acc[i][j] = (v4i){0, 0, 0, 0};

    for (int kt = 0; kt < K_DIM; kt += BK) {
        __syncthreads();   // previous compute done before overwriting LDS
#pragma unroll
        for (int b = 0; b < 2; ++b) {
            const int idx = b * 256 + t;        // 0..511 transfer index
            const int row = idx >> 2;           // 0..127
            const int seg = (idx & 3) * 16;     // 0/16/32/48 within BK
            const int8_t* ga = A + (size_t)(brow + row) * K_DIM + kt + seg;
            const int8_t* gb = B + (size_t)(bcol + row) * K_DIM + kt + seg;
            __builtin_amdgcn_global_load_lds(
                (const __attribute__((address_space(1))) void*)ga,
                (__attribute__((address_space(3))) void*)(ldsA + idx * 16),
                16, 0, 0);
            __builtin_amdgcn_global_load_lds(
                (const __attribute__((address_space(1))) void*)gb,
                (__attribute__((address_space(3))) void*)(ldsB + idx * 16),
                16, 0, 0);
        }
        __syncthreads();   // compiler emits vmcnt(0) drain before barrier

        v4i a[4], bf[4];
#pragma unroll
        for (int rb = 0; rb < 4; ++rb) {
            const int r = wr * 64 + rb * 16 + (lane & 15);
            a[rb] = *reinterpret_cast<const v4i*>(&ldsA[r * BK + (lane >> 4) * 16]);
        }
#pragma unroll
        for (int cb = 0; cb < 4; ++cb) {
            const int c = wc * 64 + cb * 16 + (lane & 15);
            bf[cb] = *reinterpret_cast<const v4i*>(&ldsB[c * BK + (lane >> 4) * 16]);
        }
#pragma unroll
        for (int rb = 0; rb < 4; ++rb)
#pragma unroll
            for (int cb = 0; cb < 4; ++cb)
                acc[rb][cb] = __builtin_amdgcn_mfma_i32_16x16x64_i8(
                    a[rb], bf[cb], acc[rb][cb], 0, 0, 0);
    }

    // Epilogue: C/D layout col = lane&15, row = (lane>>4)*4 + reg
#pragma unroll
    for (int rb = 0; rb < 4; ++rb) {
        const int rbase = brow + wr * 64 + rb * 16 + (lane >> 4) * 4;
        float sc[4];
#pragma unroll
        for (int j = 0; j < 4; ++j) sc[j] = sA[rbase + j] * ws;
#pragma unroll
        for (int cb = 0; cb < 4; ++cb) {
            const int col = bcol + wc * 64 + cb * 16 + (lane & 15);
#pragma unroll
            for (int j = 0; j < 4; ++j)
                C[(size_t)(rbase + j) * N + col] = (float)acc[rb][cb][j] * sc[j];
        }
    }
}

extern "C" void kernel_launch(void* const* d_in, const int* in_sizes, int n_in,
                              void* d_out, int out_size, void* d_ws, size_t ws_size,
                              hipStream_t stream) {
    const float* x      = (const float*)d_in[0];
    const int*   w32    = (const int*)d_in[1];     // int8 widened to int32 by harness
    const float* wscale = (const float*)d_in[2];
    float*       out    = (float*)d_out;

    const int M = in_sizes[0] / K_DIM;   // 8192
    const int N = in_sizes[1] / K_DIM;   // 4096

    int8_t* q      = (int8_t*)d_ws;
    float*  scales = (float*)((char*)d_ws + (size_t)M * K_DIM);
    int8_t* w8     = (int8_t*)((char*)d_ws + (size_t)M * K_DIM + (size_t)M * sizeof(float));

    const int total16 = (N * K_DIM) / 16;
    pack_weight<<<(total16 + 255) / 256, 256, 0, stream>>>(w32, w8, total16);

    quant_rows<<<M, 256, 0, stream>>>(x, q, scales);

    dim3 grid(N / BN, M / BM);
    gemm_i8<<<grid, 256, 0, stream>>>(q, w8, scales, wscale, out, M, N);
}

// Round 3
// 200.473 us; speedup vs baseline: 1.1622x; 1.1622x over previous
//
#include <hip/hip_runtime.h>
#include <cstdint>

typedef int v4i __attribute__((ext_vector_type(4)));

#define K_DIM 4096
#define BM 256
#define BN 256
#define BK 64
#define NT (K_DIM / BK)          // 64 K-tiles
#define TILE_BYTES (BM * BK)     // 16 KiB per operand tile
#define BUF_STRIDE (2 * TILE_BYTES)

// ---------------------------------------------------------------------------
// Kernel 0: pack int32 weight (values 1..128) -> int8.
// ---------------------------------------------------------------------------
__global__ __launch_bounds__(256) void pack_weight(
    const int* __restrict__ w32, int8_t* __restrict__ w8, int total16)
{
    const int i = blockIdx.x * 256 + threadIdx.x;
    if (i >= total16) return;
    const v4i* src = reinterpret_cast<const v4i*>(w32) + i * 4;
    v4i out;
#pragma unroll
    for (int j = 0; j < 4; ++j) {
        const v4i v = src[j];
        out[j] = (v.x & 0xff) | ((v.y & 0xff) << 8) |
                 ((v.z & 0xff) << 16) | ((unsigned)(v.w & 0xff) << 24);
    }
    reinterpret_cast<v4i*>(w8)[i] = out;
}

// ---------------------------------------------------------------------------
// Kernel 1: per-row symmetric int8 quantization (unchanged, verified).
// ---------------------------------------------------------------------------
__global__ __launch_bounds__(256) void quant_rows(
    const float* __restrict__ x, int8_t* __restrict__ q,
    float* __restrict__ scales)
{
    const int row = blockIdx.x;
    const int t   = threadIdx.x;
    const float4* xr4 = reinterpret_cast<const float4*>(x + (size_t)row * K_DIM);

    float4 v[4];
    float m = 0.0f;
#pragma unroll
    for (int i = 0; i < 4; ++i) {
        v[i] = xr4[i * 256 + t];
        m = fmaxf(m, fmaxf(fmaxf(fabsf(v[i].x), fabsf(v[i].y)),
                           fmaxf(fabsf(v[i].z), fabsf(v[i].w))));
    }
#pragma unroll
    for (int off = 32; off >= 1; off >>= 1)
        m = fmaxf(m, __shfl_xor(m, off, 64));

    __shared__ float wmax[4];
    if ((t & 63) == 0) wmax[t >> 6] = m;
    __syncthreads();
    const float am = fmaxf(fmaxf(wmax[0], wmax[1]), fmaxf(wmax[2], wmax[3]));
    const float s  = fmaxf(am / 127.0f, 1e-8f);
    if (t == 0) scales[row] = s;

    int* qi = reinterpret_cast<int*>(q + (size_t)row * K_DIM);
#pragma unroll
    for (int i = 0; i < 4; ++i) {
        const float e[4] = {v[i].x, v[i].y, v[i].z, v[i].w};
        unsigned packed = 0;
#pragma unroll
        for (int j = 0; j < 4; ++j) {
            float r = rintf(e[j] / s);
            r = fminf(fmaxf(r, -127.0f), 127.0f);
            packed |= ((unsigned)((int)r & 0xff)) << (8 * j);
        }
        qi[i * 256 + t] = (int)packed;
    }
}

// ---------------------------------------------------------------------------
// Kernel 2: int8 GEMM, 256x256 tile, BK=64, 8 waves (2Mx4N), triple-buffered
// LDS with counted vmcnt(4) (T4), 2 phases/tile of 16 MFMA (T3), XOR bank
// swizzle col16 ^= (row>>1)&3 (T2, via pre-swizzled global source since
// global_load_lds writes linearly), setprio around MFMA (T5).
//
// Race-freedom: tile t lives in buf[t%3]; its 4 loads are issued during tile
// t-2's phases. At tile-t entry, each wave's in-order vmcnt(4) retires its
// own 4 oldest loads (= tile t's); the barrier then makes them all visible.
// Tile t+1's 4 loads stay in flight (counted, never 0). Buffer t%3 is next
// overwritten by tile t+3's stages, issued during t+1's phases — after tile
// t's lgkmcnt(0)-drained ds_reads.
// ---------------------------------------------------------------------------
__global__ __launch_bounds__(512, 2) void gemm_i8(
    const int8_t* __restrict__ A,   // [M][K] quantized activations
    const int8_t* __restrict__ B,   // [N][K] packed weight
    const float* __restrict__ sA,   // [M] per-row scales
    const float* __restrict__ wsc,  // [1] weight scale
    float* __restrict__ C,          // [M][N]
    int M, int N)
{
    __shared__ int8_t lds[3 * BUF_STRIDE];   // 96 KiB

    const int t    = threadIdx.x;
    const int lane = t & 63;
    const int w    = t >> 6;
    const int wr   = w >> 2;        // 0..1 -> 128-row half
    const int wc   = w & 3;         // 0..3 -> 64-col slice

    // T1: XCD-aware block swizzle (nwg = 512, divisible by 8)
    const int nwg = gridDim.x;
    int bid = blockIdx.x;
    if ((nwg & 7) == 0) bid = (bid & 7) * (nwg >> 3) + (bid >> 3);
    const int ntn  = N / BN;
    const int brow = (bid / ntn) * BM;
    const int bcol = (bid % ntn) * BN;

    // ---- staging addresses: linear LDS dest, inverse-swizzled global src ---
    const int idx0 = t;          // chunk 0..511
    const int idx1 = t + 512;    // chunk 512..1023
    const int r0 = idx0 >> 2, r1 = idx1 >> 2;                 // row 0..255
    const int c0 = (((idx0 & 3) ^ ((r0 >> 1) & 3)) << 4);     // swizzled col
    const int c1 = (((idx1 & 3) ^ ((r1 >> 1) & 3)) << 4);
    const int8_t* gA0 = A + (size_t)(brow + r0) * K_DIM + c0;
    const int8_t* gA1 = A + (size_t)(brow + r1) * K_DIM + c1;
    const int8_t* gB0 = B + (size_t)(bcol + r0) * K_DIM + c0;
    const int8_t* gB1 = B + (size_t)(bcol + r1) * K_DIM + c1;
    const int dst0 = idx0 * 16, dst1 = idx1 * 16;

#define GLDS(gp, off) \
    __builtin_amdgcn_global_load_lds( \
        (const __attribute__((address_space(1))) void*)(gp), \
        (__attribute__((address_space(3))) void*)(lds + (off)), 16, 0, 0)
#define STAGE_A(buf, tt) do { \
    GLDS(gA0 + (size_t)(tt) * BK, (buf) * BUF_STRIDE + dst0); \
    GLDS(gA1 + (size_t)(tt) * BK, (buf) * BUF_STRIDE + dst1); } while (0)
#define STAGE_B(buf, tt) do { \
    GLDS(gB0 + (size_t)(tt) * BK, (buf) * BUF_STRIDE + TILE_BYTES + dst0); \
    GLDS(gB1 + (size_t)(tt) * BK, (buf) * BUF_STRIDE + TILE_BYTES + dst1); } while (0)

    // ---- swizzled LDS read offsets (per-thread constants) ------------------
    const int c16 = lane >> 4;           // 16B column 0..3 (K 0..63)
    int offA[2][4], offB[4];
#pragma unroll
    for (int mh = 0; mh < 2; ++mh)
#pragma unroll
        for (int m = 0; m < 4; ++m) {
            const int row = wr * 128 + mh * 64 + m * 16 + (lane & 15);
            offA[mh][m] = row * BK + ((c16 ^ ((row >> 1) & 3)) << 4);
        }
#pragma unroll
    for (int n = 0; n < 4; ++n) {
        const int row = wc * 64 + n * 16 + (lane & 15);
        offB[n] = TILE_BYTES + row * BK + ((c16 ^ ((row >> 1) & 3)) << 4);
    }

    v4i acc[8][4];
#pragma unroll
    for (int m = 0; m < 8; ++m)
#pragma unroll
        for (int n = 0; n < 4; ++n)
            acc[m][n] = (v4i){0, 0, 0, 0};

    // ---- prologue: stage tiles 0 and 1 ------------------------------------
    STAGE_A(0, 0); STAGE_B(0, 0);
    STAGE_A(1, 1); STAGE_B(1, 1);
    asm volatile("s_waitcnt vmcnt(4)" ::: "memory");   // tile 0 resident
    __builtin_amdgcn_s_barrier();

#define MFMA_Q(BASE) do { \
    acc[BASE+0][0] = __builtin_amdgcn_mfma_i32_16x16x64_i8(a0, b0, acc[BASE+0][0], 0,0,0); \
    acc[BASE+0][1] = __builtin_amdgcn_mfma_i32_16x16x64_i8(a0, b1, acc[BASE+0][1], 0,0,0); \
    acc[BASE+0][2] = __builtin_amdgcn_mfma_i32_16x16x64_i8(a0, b2, acc[BASE+0][2], 0,0,0); \
    acc[BASE+0][3] = __builtin_amdgcn_mfma_i32_16x16x64_i8(a0, b3, acc[BASE+0][3], 0,0,0); \
    acc[BASE+1][0] = __builtin_amdgcn_mfma_i32_16x16x64_i8(a1, b0, acc[BASE+1][0], 0,0,0); \
    acc[BASE+1][1] = __builtin_amdgcn_mfma_i32_16x16x64_i8(a1, b1, acc[BASE+1][1], 0,0,0); \
    acc[BASE+1][2] = __builtin_amdgcn_mfma_i32_16x16x64_i8(a1, b2, acc[BASE+1][2], 0,0,0); \
    acc[BASE+1][3] = __builtin_amdgcn_mfma_i32_16x16x64_i8(a1, b3, acc[BASE+1][3], 0,0,0); \
    acc[BASE+2][0] = __builtin_amdgcn_mfma_i32_16x16x64_i8(a2, b0, acc[BASE+2][0], 0,0,0); \
    acc[BASE+2][1] = __builtin_amdgcn_mfma_i32_16x16x64_i8(a2, b1, acc[BASE+2][1], 0,0,0); \
    acc[BASE+2][2] = __builtin_amdgcn_mfma_i32_16x16x64_i8(a2, b2, acc[BASE+2][2], 0,0,0); \
    acc[BASE+2][3] = __builtin_amdgcn_mfma_i32_16x16x64_i8(a2, b3, acc[BASE+2][3], 0,0,0); \
    acc[BASE+3][0] = __builtin_amdgcn_mfma_i32_16x16x64_i8(a3, b0, acc[BASE+3][0], 0,0,0); \
    acc[BASE+3][1] = __builtin_amdgcn_mfma_i32_16x16x64_i8(a3, b1, acc[BASE+3][1], 0,0,0); \
    acc[BASE+3][2] = __builtin_amdgcn_mfma_i32_16x16x64_i8(a3, b2, acc[BASE+3][2], 0,0,0); \
    acc[BASE+3][3] = __builtin_amdgcn_mfma_i32_16x16x64_i8(a3, b3, acc[BASE+3][3], 0,0,0); \
    } while (0)

    int cur = 0, nx = 2;
    for (int tt = 0; tt < NT; ++tt) {
        const int8_t* bufc = lds + cur * BUF_STRIDE;
        v4i a0, a1, a2, a3, b0, b1, b2, b3;
        // ================= phase 0: m-half 0, all B ========================
        a0 = *(const v4i*)(bufc + offA[0][0]);
        a1 = *(const v4i*)(bufc + offA[0][1]);
        a2 = *(const v4i*)(bufc + offA[0][2]);
        a3 = *(const v4i*)(bufc + offA[0][3]);
        b0 = *(const v4i*)(bufc + offB[0]);
        b1 = *(const v4i*)(bufc + offB[1]);
        b2 = *(const v4i*)(bufc + offB[2]);
        b3 = *(const v4i*)(bufc + offB[3]);
        if (tt + 2 < NT) STAGE_A(nx, tt + 2);
        __builtin_amdgcn_s_barrier();
        asm volatile("s_waitcnt lgkmcnt(0)" ::: "memory");
        __builtin_amdgcn_s_setprio(1);
        MFMA_Q(0);
        __builtin_amdgcn_s_setprio(0);
        __builtin_amdgcn_s_barrier();
        // ================= phase 1: m-half 1, reuse B ======================
        a0 = *(const v4i*)(bufc + offA[1][0]);
        a1 = *(const v4i*)(bufc + offA[1][1]);
        a2 = *(const v4i*)(bufc + offA[1][2]);
        a3 = *(const v4i*)(bufc + offA[1][3]);
        if (tt + 2 < NT) STAGE_B(nx, tt + 2);
        __builtin_amdgcn_s_barrier();
        asm volatile("s_waitcnt lgkmcnt(0)" ::: "memory");
        __builtin_amdgcn_s_setprio(1);
        MFMA_Q(4);
        __builtin_amdgcn_s_setprio(0);
        // counted vmcnt for next tile (never 0 in steady state)
        if (tt + 2 < NT)      asm volatile("s_waitcnt vmcnt(4)" ::: "memory");
        else if (tt + 1 < NT) asm volatile("s_waitcnt vmcnt(0)" ::: "memory");
        __builtin_amdgcn_s_barrier();
        cur = (cur == 2) ? 0 : cur + 1;
        nx  = (nx  == 2) ? 0 : nx  + 1;
    }

    // ---- epilogue: C/D layout col = lane&15, row = (lane>>4)*4 + reg ------
    const float wsv = wsc[0];
#pragma unroll
    for (int m = 0; m < 8; ++m) {
        const int rbase = brow + wr * 128 + m * 16 + (lane >> 4) * 4;
        float sc[4];
#pragma unroll
        for (int j = 0; j < 4; ++j) sc[j] = sA[rbase + j] * wsv;
#pragma unroll
        for (int n = 0; n < 4; ++n) {
            const int col = bcol + wc * 64 + n * 16 + (lane & 15);
#pragma unroll
            for (int j = 0; j < 4; ++j)
                C[(size_t)(rbase + j) * N + col] = (float)acc[m][n][j] * sc[j];
        }
    }
#undef GLDS
#undef STAGE_A
#undef STAGE_B
#undef MFMA_Q
}

extern "C" void kernel_launch(void* const* d_in, const int* in_sizes, int n_in,
                              void* d_out, int out_size, void* d_ws, size_t ws_size,
                              hipStream_t stream) {
    const float* x      = (const float*)d_in[0];
    const int*   w32    = (const int*)d_in[1];     // int8 widened to int32
    const float* wscale = (const float*)d_in[2];
    float*       out    = (float*)d_out;

    const int M = in_sizes[0] / K_DIM;   // 8192
    const int N = in_sizes[1] / K_DIM;   // 4096

    int8_t* q      = (int8_t*)d_ws;
    float*  scales = (float*)((char*)d_ws + (size_t)M * K_DIM);
    int8_t* w8     = (int8_t*)((char*)d_ws + (size_t)M * K_DIM + (size_t)M * sizeof(float));

    const int total16 = (N * K_DIM) / 16;
    pack_weight<<<(total16 + 255) / 256, 256, 0, stream>>>(w32, w8, total16);

    quant_rows<<<M, 256, 0, stream>>>(x, q, scales);

    const int nblk = (M / BM) * (N / BN);   // 512
    gemm_i8<<<nblk, 512, 0, stream>>>(q, w8, scales, wscale, out, M, N);
}

// Round 4
// 196.468 us; speedup vs baseline: 1.1858x; 1.0204x over previous
//
#include <hip/hip_runtime.h>
#include <cstdint>

typedef int v4i __attribute__((ext_vector_type(4)));

#define K_DIM 4096
#define BM 256
#define BN 256
#define BK 64
#define NT (K_DIM / BK)          // 64 K-tiles
#define TILE_BYTES (BM * BK)     // 16 KiB per operand tile
#define BUF_STRIDE (2 * TILE_BYTES)   // A tile + B tile = 32 KiB
#define NBUF 4                   // 128 KiB LDS, stage-ahead depth 3

// ---------------------------------------------------------------------------
// Kernel 0: pack int32 weight -> int8.
// ---------------------------------------------------------------------------
__global__ __launch_bounds__(256) void pack_weight(
    const int* __restrict__ w32, int8_t* __restrict__ w8, int total16)
{
    const int i = blockIdx.x * 256 + threadIdx.x;
    if (i >= total16) return;
    const v4i* src = reinterpret_cast<const v4i*>(w32) + i * 4;
    v4i out;
#pragma unroll
    for (int j = 0; j < 4; ++j) {
        const v4i v = src[j];
        out[j] = (v.x & 0xff) | ((v.y & 0xff) << 8) |
                 ((v.z & 0xff) << 16) | ((unsigned)(v.w & 0xff) << 24);
    }
    reinterpret_cast<v4i*>(w8)[i] = out;
}

// ---------------------------------------------------------------------------
// Kernel 1: per-row symmetric int8 quantization (verified, memory-floor).
// ---------------------------------------------------------------------------
__global__ __launch_bounds__(256) void quant_rows(
    const float* __restrict__ x, int8_t* __restrict__ q,
    float* __restrict__ scales)
{
    const int row = blockIdx.x;
    const int t   = threadIdx.x;
    const float4* xr4 = reinterpret_cast<const float4*>(x + (size_t)row * K_DIM);

    float4 v[4];
    float m = 0.0f;
#pragma unroll
    for (int i = 0; i < 4; ++i) {
        v[i] = xr4[i * 256 + t];
        m = fmaxf(m, fmaxf(fmaxf(fabsf(v[i].x), fabsf(v[i].y)),
                           fmaxf(fabsf(v[i].z), fabsf(v[i].w))));
    }
#pragma unroll
    for (int off = 32; off >= 1; off >>= 1)
        m = fmaxf(m, __shfl_xor(m, off, 64));

    __shared__ float wmax[4];
    if ((t & 63) == 0) wmax[t >> 6] = m;
    __syncthreads();
    const float am = fmaxf(fmaxf(wmax[0], wmax[1]), fmaxf(wmax[2], wmax[3]));
    const float s  = fmaxf(am / 127.0f, 1e-8f);
    if (t == 0) scales[row] = s;

    int* qi = reinterpret_cast<int*>(q + (size_t)row * K_DIM);
#pragma unroll
    for (int i = 0; i < 4; ++i) {
        const float e[4] = {v[i].x, v[i].y, v[i].z, v[i].w};
        unsigned packed = 0;
#pragma unroll
        for (int j = 0; j < 4; ++j) {
            float r = rintf(e[j] / s);
            r = fminf(fmaxf(r, -127.0f), 127.0f);
            packed |= ((unsigned)((int)r & 0xff)) << (8 * j);
        }
        qi[i * 256 + t] = (int)packed;
    }
}

// ---------------------------------------------------------------------------
// Kernel 2: int8 GEMM, 256x256 tile, BK=64, 8 waves (2Mx4N).
// Cross-phase register pipelining: fragments for phase p are ds_read-issued
// in phase p-1 (inline asm, counted lgkmcnt 4/8, never 0 mid-loop).
// 4 LDS buffers, stage tile t+3 during tile t, ONE barrier per tile with
// vmcnt(4) (retires tiles t+1,t+2-resident invariant; never drains to 0).
//
// Invariant entering tile t (after boundary barrier): tiles t and t+1
// resident+visible in buf[t&3], buf[(t+1)&3]; tile t+2's 4 loads in flight;
// tile t+3 staged during t into buf[(t+3)&3], whose previous contents'
// (tile t-1) reads were lgkm-drained before the preceding barrier.
// ---------------------------------------------------------------------------
__global__ __launch_bounds__(512, 2) void gemm_i8(
    const int8_t* __restrict__ A,   // [M][K] quantized activations
    const int8_t* __restrict__ B,   // [N][K] packed weight
    const float* __restrict__ sA,   // [M] per-row scales
    const float* __restrict__ wsc,  // [1] weight scale
    float* __restrict__ C,          // [M][N]
    int M, int N)
{
    __shared__ int8_t lds[NBUF * BUF_STRIDE];   // 128 KiB

    const int t    = threadIdx.x;
    const int lane = t & 63;
    const int w    = t >> 6;
    const int wr   = w >> 2;        // 0..1 -> 128-row half
    const int wc   = w & 3;         // 0..3 -> 64-col slice

    // T1: XCD-aware block swizzle (nwg = 512, divisible by 8)
    const int nwg = gridDim.x;
    int bid = blockIdx.x;
    if ((nwg & 7) == 0) bid = (bid & 7) * (nwg >> 3) + (bid >> 3);
    const int ntn  = N / BN;
    const int brow = (bid / ntn) * BM;
    const int bcol = (bid % ntn) * BN;

    // ---- staging: linear LDS dest, inverse-swizzled global src (verified) --
    const int idx0 = t;
    const int idx1 = t + 512;
    const int r0 = idx0 >> 2, r1 = idx1 >> 2;
    const int c0 = (((idx0 & 3) ^ ((r0 >> 1) & 3)) << 4);
    const int c1 = (((idx1 & 3) ^ ((r1 >> 1) & 3)) << 4);
    const int8_t* gA0 = A + (size_t)(brow + r0) * K_DIM + c0;
    const int8_t* gA1 = A + (size_t)(brow + r1) * K_DIM + c1;
    const int8_t* gB0 = B + (size_t)(bcol + r0) * K_DIM + c0;
    const int8_t* gB1 = B + (size_t)(bcol + r1) * K_DIM + c1;
    const int dst0 = idx0 * 16, dst1 = idx1 * 16;

#define GLDS(gp, off) \
    __builtin_amdgcn_global_load_lds( \
        (const __attribute__((address_space(1))) void*)(gp), \
        (__attribute__((address_space(3))) void*)(lds + (off)), 16, 0, 0)
#define STAGE_A(buf, tt) do { \
    GLDS(gA0 + (size_t)(tt) * BK, (buf) * BUF_STRIDE + dst0); \
    GLDS(gA1 + (size_t)(tt) * BK, (buf) * BUF_STRIDE + dst1); } while (0)
#define STAGE_B(buf, tt) do { \
    GLDS(gB0 + (size_t)(tt) * BK, (buf) * BUF_STRIDE + TILE_BYTES + dst0); \
    GLDS(gB1 + (size_t)(tt) * BK, (buf) * BUF_STRIDE + TILE_BYTES + dst1); } while (0)

    // ---- swizzled LDS frag byte-offsets (lds[] is at LDS offset 0) ---------
    const int c16 = lane >> 4;
    unsigned offA0[4], offA1[4], offB[4];
#pragma unroll
    for (int m = 0; m < 4; ++m) {
        int row0 = wr * 128 + m * 16 + (lane & 15);
        int row1 = row0 + 64;
        offA0[m] = row0 * BK + ((c16 ^ ((row0 >> 1) & 3)) << 4);
        offA1[m] = row1 * BK + ((c16 ^ ((row1 >> 1) & 3)) << 4);
    }
#pragma unroll
    for (int n = 0; n < 4; ++n) {
        int row = wc * 64 + n * 16 + (lane & 15);
        offB[n] = TILE_BYTES + row * BK + ((c16 ^ ((row >> 1) & 3)) << 4);
    }

#define DSREAD(dst, addr) \
    asm volatile("ds_read_b128 %0, %1" : "=v"(dst) : "v"(addr))

    v4i acc[8][4];
#pragma unroll
    for (int m = 0; m < 8; ++m)
#pragma unroll
        for (int n = 0; n < 4; ++n)
            acc[m][n] = (v4i){0, 0, 0, 0};

    v4i a0[4], a1[4], bA[4], bB[4];

    // ---- prologue: stage tiles 0,1,2; wait tiles 0,1 resident --------------
    STAGE_A(0, 0); STAGE_B(0, 0);
    STAGE_A(1, 1); STAGE_B(1, 1);
    STAGE_A(2, 2); STAGE_B(2, 2);
    asm volatile("s_waitcnt vmcnt(4)" ::: "memory");   // retire tiles 0,1
    __builtin_amdgcn_s_barrier();
    __builtin_amdgcn_sched_barrier(0);

    // pre-read tile 0: A-half0 + B  (8 ds_reads outstanding entering loop)
    DSREAD(a0[0], offA0[0]); DSREAD(a0[1], offA0[1]);
    DSREAD(a0[2], offA0[2]); DSREAD(a0[3], offA0[3]);
    DSREAD(bA[0], offB[0]);  DSREAD(bA[1], offB[1]);
    DSREAD(bA[2], offB[2]);  DSREAD(bA[3], offB[3]);

#define MFMA_Q(BASE, AV, BV) do { \
    acc[BASE+0][0] = __builtin_amdgcn_mfma_i32_16x16x64_i8(AV[0], BV[0], acc[BASE+0][0], 0,0,0); \
    acc[BASE+0][1] = __builtin_amdgcn_mfma_i32_16x16x64_i8(AV[0], BV[1], acc[BASE+0][1], 0,0,0); \
    acc[BASE+0][2] = __builtin_amdgcn_mfma_i32_16x16x64_i8(AV[0], BV[2], acc[BASE+0][2], 0,0,0); \
    acc[BASE+0][3] = __builtin_amdgcn_mfma_i32_16x16x64_i8(AV[0], BV[3], acc[BASE+0][3], 0,0,0); \
    acc[BASE+1][0] = __builtin_amdgcn_mfma_i32_16x16x64_i8(AV[1], BV[0], acc[BASE+1][0], 0,0,0); \
    acc[BASE+1][1] = __builtin_amdgcn_mfma_i32_16x16x64_i8(AV[1], BV[1], acc[BASE+1][1], 0,0,0); \
    acc[BASE+1][2] = __builtin_amdgcn_mfma_i32_16x16x64_i8(AV[1], BV[2], acc[BASE+1][2], 0,0,0); \
    acc[BASE+1][3] = __builtin_amdgcn_mfma_i32_16x16x64_i8(AV[1], BV[3], acc[BASE+1][3], 0,0,0); \
    acc[BASE+2][0] = __builtin_amdgcn_mfma_i32_16x16x64_i8(AV[2], BV[0], acc[BASE+2][0], 0,0,0); \
    acc[BASE+2][1] = __builtin_amdgcn_mfma_i32_16x16x64_i8(AV[2], BV[1], acc[BASE+2][1], 0,0,0); \
    acc[BASE+2][2] = __builtin_amdgcn_mfma_i32_16x16x64_i8(AV[2], BV[2], acc[BASE+2][2], 0,0,0); \
    acc[BASE+2][3] = __builtin_amdgcn_mfma_i32_16x16x64_i8(AV[2], BV[3], acc[BASE+2][3], 0,0,0); \
    acc[BASE+3][0] = __builtin_amdgcn_mfma_i32_16x16x64_i8(AV[3], BV[0], acc[BASE+3][0], 0,0,0); \
    acc[BASE+3][1] = __builtin_amdgcn_mfma_i32_16x16x64_i8(AV[3], BV[1], acc[BASE+3][1], 0,0,0); \
    acc[BASE+3][2] = __builtin_amdgcn_mfma_i32_16x16x64_i8(AV[3], BV[2], acc[BASE+3][2], 0,0,0); \
    acc[BASE+3][3] = __builtin_amdgcn_mfma_i32_16x16x64_i8(AV[3], BV[3], acc[BASE+3][3], 0,0,0); \
    } while (0)

    // One tile: phase0 consumes (a0,BU) loaded last phase, prefetches a1;
    // phase1 consumes (a1,BU), prefetches next tile's a0 + BL; one barrier.
#define TILE_BODY(T, BU, BL) do { \
    const unsigned bufc = (unsigned)(cur * BUF_STRIDE); \
    const unsigned bufn = (unsigned)(((cur + 1) & 3) * BUF_STRIDE); \
    const int nx3 = (cur + 3) & 3; \
    /* -------- phase 0 -------- */ \
    DSREAD(a1[0], bufc + offA1[0]); DSREAD(a1[1], bufc + offA1[1]); \
    DSREAD(a1[2], bufc + offA1[2]); DSREAD(a1[3], bufc + offA1[3]); \
    if ((T) + 3 < NT) STAGE_A(nx3, (T) + 3); \
    asm volatile("s_waitcnt lgkmcnt(4)" ::: "memory"); \
    __builtin_amdgcn_sched_barrier(0); \
    __builtin_amdgcn_s_setprio(1); \
    MFMA_Q(0, a0, BU); \
    __builtin_amdgcn_s_setprio(0); \
    __builtin_amdgcn_sched_barrier(0); \
    /* -------- phase 1 -------- */ \
    if ((T) + 1 < NT) { \
        DSREAD(a0[0], bufn + offA0[0]); DSREAD(a0[1], bufn + offA0[1]); \
        DSREAD(a0[2], bufn + offA0[2]); DSREAD(a0[3], bufn + offA0[3]); \
        DSREAD(BL[0], bufn + offB[0]);  DSREAD(BL[1], bufn + offB[1]); \
        DSREAD(BL[2], bufn + offB[2]);  DSREAD(BL[3], bufn + offB[3]); \
    } \
    if ((T) + 3 < NT) STAGE_B(nx3, (T) + 3); \
    if ((T) + 1 < NT) asm volatile("s_waitcnt lgkmcnt(8)" ::: "memory"); \
    else              asm volatile("s_waitcnt lgkmcnt(0)" ::: "memory"); \
    __builtin_amdgcn_sched_barrier(0); \
    __builtin_amdgcn_s_setprio(1); \
    MFMA_Q(4, a1, BU); \
    __builtin_amdgcn_s_setprio(0); \
    __builtin_amdgcn_sched_barrier(0); \
    /* -------- tile boundary: counted vmcnt + single barrier -------- */ \
    if ((T) + 1 < NT) { \
        if ((T) + 3 < NT) asm volatile("s_waitcnt vmcnt(4)" ::: "memory"); \
        else              asm volatile("s_waitcnt vmcnt(0)" ::: "memory"); \
        __builtin_amdgcn_s_barrier(); \
        __builtin_amdgcn_sched_barrier(0); \
    } \
    cur = (cur + 1) & 3; \
    } while (0)

    int cur = 0;
    for (int tt = 0; tt < NT; tt += 2) {
        TILE_BODY(tt,     bA, bB);   // use bA, prefetch into bB
        TILE_BODY(tt + 1, bB, bA);   // use bB, prefetch into bA
    }

    // ---- epilogue: C/D layout col = lane&15, row = (lane>>4)*4 + reg ------
    const float wsv = wsc[0];
#pragma unroll
    for (int m = 0; m < 8; ++m) {
        const int rbase = brow + wr * 128 + m * 16 + (lane >> 4) * 4;
        float sc[4];
#pragma unroll
        for (int j = 0; j < 4; ++j) sc[j] = sA[rbase + j] * wsv;
#pragma unroll
        for (int n = 0; n < 4; ++n) {
            const int col = bcol + wc * 64 + n * 16 + (lane & 15);
#pragma unroll
            for (int j = 0; j < 4; ++j)
                C[(size_t)(rbase + j) * N + col] = (float)acc[m][n][j] * sc[j];
        }
    }
#undef GLDS
#undef STAGE_A
#undef STAGE_B
#undef DSREAD
#undef MFMA_Q
#undef TILE_BODY
}

extern "C" void kernel_launch(void* const* d_in, const int* in_sizes, int n_in,
                              void* d_out, int out_size, void* d_ws, size_t ws_size,
                              hipStream_t stream) {
    const float* x      = (const float*)d_in[0];
    const int*   w32    = (const int*)d_in[1];     // int8 widened to int32
    const float* wscale = (const float*)d_in[2];
    float*       out    = (float*)d_out;

    const int M = in_sizes[0] / K_DIM;   // 8192
    const int N = in_sizes[1] / K_DIM;   // 4096

    int8_t* q      = (int8_t*)d_ws;
    float*  scales = (float*)((char*)d_ws + (size_t)M * K_DIM);
    int8_t* w8     = (int8_t*)((char*)d_ws + (size_t)M * K_DIM + (size_t)M * sizeof(float));

    const int total16 = (N * K_DIM) / 16;
    pack_weight<<<(total16 + 255) / 256, 256, 0, stream>>>(w32, w8, total16);

    quant_rows<<<M, 256, 0, stream>>>(x, q, scales);

    const int nblk = (M / BM) * (N / BN);   // 512
    gemm_i8<<<nblk, 512, 0, stream>>>(q, w8, scales, wscale, out, M, N);
}